// Round 10
// baseline (446.391 us; speedup 1.0000x reference)
//
#include <hip/hip_runtime.h>
#include <cstdint>
#include <cstddef>

typedef unsigned short u16;
typedef __attribute__((ext_vector_type(8))) short bhalf8;   // 8 x bf16 (4 VGPRs)
typedef __attribute__((ext_vector_type(4))) float fx4;      // MFMA 16x16 accumulator
typedef __attribute__((ext_vector_type(4))) unsigned short u16x4;

#define T_SEQ 2048
#define NHEAD 25
#define QKV_LD 4864   // padded 3C row stride (4800 -> 38*128) so 128-wide N-tiles divide evenly
#define WOUT_LD 1664  // padded out-proj N (1600 -> 13*128)

static __device__ __forceinline__ u16 f2bf(float f) {
  union { float f; uint32_t u; } v; v.f = f;
  uint32_t r = (v.u + 0x7FFFu + ((v.u >> 16) & 1u)) >> 16;  // RNE
  return (u16)r;
}

static __device__ __forceinline__ fx4 mfma16(bhalf8 a, bhalf8 b, fx4 c) {
  return __builtin_amdgcn_mfma_f32_16x16x32_bf16(a, b, c, 0, 0, 0);
}

// async global->LDS, 16B per lane. LDS dest: wave-uniform base + lane*16 (linear!).
static __device__ __forceinline__ void async16(const void* g, void* l) {
  __builtin_amdgcn_global_load_lds(
      (__attribute__((address_space(1))) unsigned int*)(void*)g,
      (__attribute__((address_space(3))) unsigned int*)l, 16, 0, 0);
}

// ---------------- convert f32 -> bf16, vectorized (G13) ----------------
__global__ void cvt_bf16_kernel(const float* __restrict__ in, u16* __restrict__ out, int n4) {
  int i = blockIdx.x * 256 + threadIdx.x;
  if (i >= n4) return;
  float4 v = ((const float4*)in)[i];
  u16x4 o;
  o.x = f2bf(v.x); o.y = f2bf(v.y); o.z = f2bf(v.z); o.w = f2bf(v.w);
  ((u16x4*)out)[i] = o;
}

// ------- transpose + convert: in [R][C] f32 -> out [C][R] bf16 (R,C % 32 == 0) -------
__global__ void transp_cvt_kernel(const float* __restrict__ in, u16* __restrict__ out,
                                  int R, int C) {
  __shared__ float tile[32][33];
  int bx = blockIdx.x * 32, by = blockIdx.y * 32;
  int tx = threadIdx.x, ty = threadIdx.y;
  #pragma unroll
  for (int i = 0; i < 32; i += 8)
    tile[ty + i][tx] = in[(size_t)(by + ty + i) * C + bx + tx];
  __syncthreads();
  #pragma unroll
  for (int i = 0; i < 32; i += 8)
    out[(size_t)(bx + ty + i) * R + by + tx] = f2bf(tile[tx][ty + i]);
}

// ---------------- GEMM: C[M,N] = A[M,K] * BT[N,K]^T + bias ----------------
// m97-structure: 128xBN tile, BK=32, 4 waves (2x2), global_load_lds(16B) staging.
// + T1 XCD swizzle (nwg % 8 == 0 for all our launches).
// OUTF32 path guards the store at gc<Nreal (B rows >= Nreal are poison pad,
// finite bf16 garbage whose products are computed then discarded).
template<int BN, bool OUTF32>
__global__ __launch_bounds__(256)
void gemm_bt_kernel(const u16* __restrict__ A, const u16* __restrict__ BT,
                    const float* __restrict__ bias, void* __restrict__ C,
                    int K, int ldc, int Nreal) {
  constexpr int BM = 128, BK = 32;
  constexpr int NF = BN / 32;                     // frags per wave along N
  constexpr int APASS = (BM * BK) / (256 * 8);    // 2
  constexpr int BPASS = (BN * BK) / (256 * 8);    // 2 (BN=128) or 1 (BN=64)
  __shared__ __align__(16) u16 Al[BM * BK];
  __shared__ __align__(16) u16 Bl[BN * BK];
  const int t = threadIdx.x;
  const int w = t >> 6, l = t & 63, lr = l & 15, lg = l >> 4;
  const int wm = w >> 1, wn = w & 1;

  // XCD-aware swizzle of the linear block id (T1; nwg%8==0 guaranteed here)
  const int nwg = gridDim.x * gridDim.y;
  const int id = blockIdx.y * gridDim.x + blockIdx.x;
  const int qq = nwg >> 3;
  const int swz = (id & 7) * qq + (id >> 3);
  const int bx = swz % gridDim.x, by = swz / gridDim.x;

  const int m0 = by * BM, n0 = bx * BN;

  fx4 acc[4][NF] = {};

  for (int k0 = 0; k0 < K; k0 += BK) {
    #pragma unroll
    for (int p = 0; p < APASS; ++p) {
      int c = t + p * 256;  // 16B chunk id; row = c>>2, col8 = (c&3)*8
      async16(A + (size_t)(m0 + (c >> 2)) * K + k0 + (c & 3) * 8, Al + c * 8);
    }
    #pragma unroll
    for (int p = 0; p < BPASS; ++p) {
      int c = t + p * 256;
      async16(BT + (size_t)(n0 + (c >> 2)) * K + k0 + (c & 3) * 8, Bl + c * 8);
    }
    __syncthreads();  // compiler drains vmcnt before barrier
    bhalf8 af[4], bfr[NF];
    #pragma unroll
    for (int m = 0; m < 4; ++m)
      af[m] = *(const bhalf8*)(Al + (wm * 64 + m * 16 + lr) * BK + lg * 8);
    #pragma unroll
    for (int n = 0; n < NF; ++n)
      bfr[n] = *(const bhalf8*)(Bl + (wn * (BN / 2) + n * 16 + lr) * BK + lg * 8);
    #pragma unroll
    for (int m = 0; m < 4; ++m)
      #pragma unroll
      for (int n = 0; n < NF; ++n)
        acc[m][n] = mfma16(af[m], bfr[n], acc[m][n]);
    __syncthreads();
  }

  // epilogue: C/D layout col=lane&15, row=(lane>>4)*4+reg (m89-verified)
  #pragma unroll
  for (int m = 0; m < 4; ++m)
  #pragma unroll
  for (int n = 0; n < NF; ++n)
  #pragma unroll
  for (int r = 0; r < 4; ++r) {
    int gr = m0 + wm * 64 + m * 16 + lg * 4 + r;
    int gc = n0 + wn * (BN / 2) + n * 16 + lr;
    float bv = (gc < Nreal) ? bias[gc] : 0.0f;
    float v = acc[m][n][r] + bv;
    if constexpr (OUTF32) {
      if (gc < Nreal) ((float*)C)[(size_t)gr * ldc + gc] = v;
    } else {
      ((u16*)C)[(size_t)gr * ldc + gc] = f2bf(v);
    }
  }
}

// ---------------- flash attention, causal, D=64 ----------------
// Round 5 (unchanged, unmeasured): 4 waves x 32 q-rows each (two 16-row
// sub-tiles sharing staged K/V fragments) = 128 q-rows/block. Halves
// wave-iterations (the measured cost unit, r1/r2/r5 invariant). KBLK=64
// double-buffered, async16 K (pre-swizzled source), reg-staged V with
// swizzled transpose scatter, ONE barrier per kv-iter, defer-max softmax.
// Swizzle: 16B slot s of row r holds data slot (s ^ (r&7)).
#define KSWZ(row, slot) (((row) << 6) + ((((slot)) ^ ((row) & 7)) << 3))

__global__ __launch_bounds__(256, 3)
void attn_kernel(const u16* __restrict__ qkv, u16* __restrict__ out) {
  const int qblk = (gridDim.x - 1) - blockIdx.x;  // big blocks first (causal tail)
  const int bh = blockIdx.y;
  const int b = bh / NHEAD, h = bh % NHEAD;
  const int t = threadIdx.x, w = t >> 6, l = t & 63;
  const int lr = l & 15, lg = l >> 4;

  __shared__ __align__(16) u16 Kl[2][64 * 64];   // K tile [kv][d], swizzled
  __shared__ __align__(16) u16 Vt[2][64 * 64];   // V^T tile [d][kv], swizzled
  __shared__ __align__(16) u16 Pl[4][32][72];    // per-wave P [qrow][kv], pad 72

  const int q0 = qblk * 128;
  const int qw = q0 + w * 32;                    // this wave's first q-row (32 rows)
  const int nkb = 2 * qblk + 2;

  // Q A-frags for both 16-row sub-tiles (g=0: rows qw..+15, g=1: +16..+31)
  bhalf8 qf[2][2];
  #pragma unroll
  for (int g = 0; g < 2; ++g) {
    const size_t qoff = ((size_t)(b * T_SEQ + qw + g * 16 + lr)) * QKV_LD + h * 64;
    qf[g][0] = *(const bhalf8*)(qkv + qoff + lg * 8);
    qf[g][1] = *(const bhalf8*)(qkv + qoff + 32 + lg * 8);
  }

  constexpr float KSC = 0.125f * 1.44269504089f;  // scale * log2(e)

  fx4 oacc[2][4] = {};
  float m_run[2][4], mk[2][4], thr[2][4], l_acc[2][4];
  #pragma unroll
  for (int g = 0; g < 2; ++g)
    #pragma unroll
    for (int r = 0; r < 4; ++r) {
      m_run[g][r] = -3.0e38f; mk[g][r] = -3.0e38f; thr[g][r] = -3.0e38f; l_acc[g][r] = 0.0f;
    }

  // --- staging thread mappings (256 threads, 2 chunks each) ---
  // chunk c in 0..511: row = c>>3 (kv 0..63), slot = c&7.
  const size_t kvrow_base = (size_t)(b * T_SEQ) * QKV_LD + 1600 + h * 64;

  int4 vpre[2];
  // prologue: issue K(0) via async16 (pre-swizzled source), V(0) to regs
  #pragma unroll
  for (int p = 0; p < 2; ++p) {
    const int c = t + p * 256;
    const int kr = c >> 3;
    const int ks = (c & 7) ^ (kr & 7);
    const size_t rb = kvrow_base + (size_t)kr * QKV_LD;
    async16(qkv + rb + ks * 8, Kl[0] + c * 8);
    vpre[p] = *(const int4*)(qkv + rb + 1600 + (c & 7) * 8);
  }

  for (int kb = 0; kb < nkb; ++kb) {
    const int bsel = kb & 1;
    const int kv0 = kb * 64;
    u16* Klb = Kl[bsel];
    u16* Vtb = Vt[bsel];

    asm volatile("s_waitcnt vmcnt(0)" ::: "memory");  // K(kb) in LDS, V(kb) in regs
    // scatter V(kb) -> Vt[bsel] (transposed, swizzled)
    #pragma unroll
    for (int p = 0; p < 2; ++p) {
      const int c = t + p * 256;
      const int vr = c >> 3;
      const int vc = (c & 7) * 8;
      union { int4 v; u16 u[8]; } vv; vv.v = vpre[p];
      #pragma unroll
      for (int i = 0; i < 8; ++i) {
        int row = vc + i;  // d
        Vtb[(row << 6) + (((vr >> 3) ^ (row & 7)) << 3) + (vr & 7)] = vv.u[i];
      }
    }
    __syncthreads();  // staging visible; nothing in flight, drain is free

    // issue next tile's loads -- they stay in flight across the whole compute
    if (kb + 1 < nkb) {
      #pragma unroll
      for (int p = 0; p < 2; ++p) {
        const int c = t + p * 256;
        const int kr = c >> 3;
        const int ks = (c & 7) ^ (kr & 7);
        const size_t rb = kvrow_base + (size_t)(kv0 + 64 + kr) * QKV_LD;
        async16(qkv + rb + ks * 8, Kl[bsel ^ 1] + c * 8);
        vpre[p] = *(const int4*)(qkv + rb + 1600 + (c & 7) * 8);
      }
    }

    const bool active = (kv0 <= qw + 31);
    if (active) {
      // ---- S_raw = Q K^T (unscaled; scale folded into exp2 fma) ----
      float sv[2][4][4];
      __builtin_amdgcn_s_setprio(1);
      #pragma unroll
      for (int n = 0; n < 4; ++n) {
        bhalf8 k0f = *(const bhalf8*)(Klb + KSWZ(n * 16 + lr, lg));
        bhalf8 k1f = *(const bhalf8*)(Klb + KSWZ(n * 16 + lr, 4 + lg));
        #pragma unroll
        for (int g = 0; g < 2; ++g) {
          fx4 s = {0.f, 0.f, 0.f, 0.f};
          s = mfma16(qf[g][0], k0f, s);
          s = mfma16(qf[g][1], k1f, s);
          #pragma unroll
          for (int r = 0; r < 4; ++r) sv[g][n][r] = s[r];
        }
      }
      __builtin_amdgcn_s_setprio(0);
      if (kv0 + 63 > qw) {  // diagonal overlap: mask kv > q
        #pragma unroll
        for (int g = 0; g < 2; ++g)
          #pragma unroll
          for (int n = 0; n < 4; ++n)
            #pragma unroll
            for (int r = 0; r < 4; ++r)
              if (kv0 + n * 16 + lr > qw + g * 16 + lg * 4 + r) sv[g][n][r] = -1e30f;
      }
      // ---- defer-max check: per-lane max vs raw threshold, wave-uniform ballot ----
      float pm[2][4];
      bool ok = true;
      #pragma unroll
      for (int g = 0; g < 2; ++g)
        #pragma unroll
        for (int r = 0; r < 4; ++r) {
          pm[g][r] = fmaxf(fmaxf(sv[g][0][r], sv[g][1][r]), fmaxf(sv[g][2][r], sv[g][3][r]));
          ok = ok && (pm[g][r] <= thr[g][r]);
        }
      if (!__all(ok)) {
        // slow path (~once per wave): full row-max reduce + rescale state
        #pragma unroll
        for (int g = 0; g < 2; ++g)
          #pragma unroll
          for (int r = 0; r < 4; ++r) {
            float mx = pm[g][r] * 0.125f;
            mx = fmaxf(mx, __shfl_xor(mx, 1));
            mx = fmaxf(mx, __shfl_xor(mx, 2));
            mx = fmaxf(mx, __shfl_xor(mx, 4));
            mx = fmaxf(mx, __shfl_xor(mx, 8));
            float mN = fmaxf(m_run[g][r], mx);
            float scl = __expf(m_run[g][r] - mN);   // -inf first time -> 0
            m_run[g][r] = mN;
            mk[g][r] = mN * 1.44269504089f;
            thr[g][r] = 8.0f * mN + 64.0f;          // raw-score form of (m+8)
            l_acc[g][r] *= scl;
            oacc[g][0][r] *= scl; oacc[g][1][r] *= scl;
            oacc[g][2][r] *= scl; oacc[g][3][r] *= scl;
          }
      }
      // ---- common path: P = exp2(S*KSC - mk); per-lane l accumulation ----
      #pragma unroll
      for (int g = 0; g < 2; ++g)
        #pragma unroll
        for (int n = 0; n < 4; ++n)
          #pragma unroll
          for (int r = 0; r < 4; ++r) {
            float p = exp2f(fmaf(sv[g][n][r], KSC, -mk[g][r]));
            l_acc[g][r] += p;
            Pl[w][g * 16 + lg * 4 + r][n * 16 + lr] = f2bf(p);
          }
      asm volatile("s_waitcnt lgkmcnt(0)" ::: "memory");  // cross-lane P visible
      __builtin_amdgcn_sched_barrier(0);                  // guide rule #18
      // ---- O += P V ----
      __builtin_amdgcn_s_setprio(1);
      #pragma unroll
      for (int s = 0; s < 2; ++s) {
        bhalf8 pa0 = *(const bhalf8*)&Pl[w][lr][s * 32 + lg * 8];
        bhalf8 pa1 = *(const bhalf8*)&Pl[w][16 + lr][s * 32 + lg * 8];
        #pragma unroll
        for (int n = 0; n < 4; ++n) {
          bhalf8 vbf = *(const bhalf8*)(Vtb + KSWZ(n * 16 + lr, s * 4 + lg));
          oacc[0][n] = mfma16(pa0, vbf, oacc[0][n]);
          oacc[1][n] = mfma16(pa1, vbf, oacc[1][n]);
        }
      }
      __builtin_amdgcn_s_setprio(0);
    }
  }

  // ---- epilogue: one cross-lane l reduction, then normalize + store ----
  #pragma unroll
  for (int g = 0; g < 2; ++g) {
    #pragma unroll
    for (int r = 0; r < 4; ++r) {
      float rs = l_acc[g][r];
      rs += __shfl_xor(rs, 1);
      rs += __shfl_xor(rs, 2);
      rs += __shfl_xor(rs, 4);
      rs += __shfl_xor(rs, 8);
      l_acc[g][r] = rs;
    }
    const size_t obase = ((size_t)(b * T_SEQ + qw + g * 16 + lg * 4)) * 1600 + h * 64;
    #pragma unroll
    for (int n = 0; n < 4; ++n)
      #pragma unroll
      for (int r = 0; r < 4; ++r) {
        float v = oacc[g][n][r] / l_acc[g][r];
        out[obase + (size_t)r * 1600 + n * 16 + lr] = f2bf(v);
      }
  }
}

extern "C" void kernel_launch(void* const* d_in, const int* in_sizes, int n_in,
                              void* d_out, int out_size, void* d_ws, size_t ws_size,
                              hipStream_t stream) {
  const float* x     = (const float*)d_in[0];  // [2,2048,1600]
  const float* w_qkv = (const float*)d_in[1];  // [1600,4800]
  const float* b_qkv = (const float*)d_in[2];  // [4800]
  const float* w_out = (const float*)d_in[3];  // [1600,1600]
  const float* b_out = (const float*)d_in[4];  // [1600]
  float* out = (float*)d_out;                  // [2,2048,1600] f32

  constexpr size_t NTOK = 4096;  // B*T
  char* ws = (char*)d_ws;
  size_t off = 0;
  u16* xb    = (u16*)(ws + off); off += NTOK * 1600 * 2;              // x bf16
  u16* wqkvT = (u16*)(ws + off); off += (size_t)QKV_LD * 1600 * 2;    // w_qkv^T bf16 (padded rows)
  u16* woutT = (u16*)(ws + off); off += (size_t)WOUT_LD * 1600 * 2;   // w_out^T bf16 (padded rows)
  u16* qkvb  = (u16*)(ws + off); off += NTOK * QKV_LD * 2;            // qkv bf16 (padded ldc)
  u16* attnb = (u16*)(ws + off); off += NTOK * 1600 * 2;              // attn out bf16
  (void)ws_size; (void)in_sizes; (void)n_in; (void)out_size;

  cvt_bf16_kernel<<<dim3((unsigned)(NTOK * 1600 / 4 / 256)), dim3(256), 0, stream>>>(
      x, xb, (int)(NTOK * 1600 / 4));
  transp_cvt_kernel<<<dim3(4800 / 32, 1600 / 32), dim3(32, 8), 0, stream>>>(
      w_qkv, wqkvT, 1600, 4800);
  transp_cvt_kernel<<<dim3(1600 / 32, 1600 / 32), dim3(32, 8), 0, stream>>>(
      w_out, woutT, 1600, 1600);
  gemm_bt_kernel<128, false><<<dim3(QKV_LD / 128, NTOK / 128), dim3(256), 0, stream>>>(
      xb, wqkvT, b_qkv, qkvb, 1600, QKV_LD, 4800);
  attn_kernel<<<dim3(T_SEQ / 128, 2 * NHEAD), dim3(256), 0, stream>>>(qkvb, attnb);
  gemm_bt_kernel<128, true><<<dim3(WOUT_LD / 128, NTOK / 128), dim3(256), 0, stream>>>(
      attnb, woutT, b_out, out, 1600, 1600, 1600);
}

// Round 11
// 380.551 us; speedup vs baseline: 1.1730x; 1.1730x over previous
//
#include <hip/hip_runtime.h>
#include <cstdint>
#include <cstddef>

typedef unsigned short u16;
typedef __attribute__((ext_vector_type(8))) short bhalf8;   // 8 x bf16 (4 VGPRs)
typedef __attribute__((ext_vector_type(4))) float fx4;      // MFMA 16x16 accumulator
typedef __attribute__((ext_vector_type(4))) unsigned short u16x4;

#define T_SEQ 2048
#define NHEAD 25
#define QKV_LD 4864   // padded 3C row stride (4800 -> 38*128) so 128-wide N-tiles divide evenly
#define WOUT_LD 1664  // padded out-proj N (1600 -> 13*128)

static __device__ __forceinline__ u16 f2bf(float f) {
  union { float f; uint32_t u; } v; v.f = f;
  uint32_t r = (v.u + 0x7FFFu + ((v.u >> 16) & 1u)) >> 16;  // RNE
  return (u16)r;
}

static __device__ __forceinline__ fx4 mfma16(bhalf8 a, bhalf8 b, fx4 c) {
  return __builtin_amdgcn_mfma_f32_16x16x32_bf16(a, b, c, 0, 0, 0);
}

// async global->LDS, 16B per lane. LDS dest: wave-uniform base + lane*16 (linear!).
static __device__ __forceinline__ void async16(const void* g, void* l) {
  __builtin_amdgcn_global_load_lds(
      (__attribute__((address_space(1))) unsigned int*)(void*)g,
      (__attribute__((address_space(3))) unsigned int*)l, 16, 0, 0);
}

// ---------------- convert f32 -> bf16, vectorized (G13) ----------------
__global__ void cvt_bf16_kernel(const float* __restrict__ in, u16* __restrict__ out, int n4) {
  int i = blockIdx.x * 256 + threadIdx.x;
  if (i >= n4) return;
  float4 v = ((const float4*)in)[i];
  u16x4 o;
  o.x = f2bf(v.x); o.y = f2bf(v.y); o.z = f2bf(v.z); o.w = f2bf(v.w);
  ((u16x4*)out)[i] = o;
}

// ------- transpose + convert: in [R][C] f32 -> out [C][R] bf16 (R,C % 32 == 0) -------
__global__ void transp_cvt_kernel(const float* __restrict__ in, u16* __restrict__ out,
                                  int R, int C) {
  __shared__ float tile[32][33];
  int bx = blockIdx.x * 32, by = blockIdx.y * 32;
  int tx = threadIdx.x, ty = threadIdx.y;
  #pragma unroll
  for (int i = 0; i < 32; i += 8)
    tile[ty + i][tx] = in[(size_t)(by + ty + i) * C + bx + tx];
  __syncthreads();
  #pragma unroll
  for (int i = 0; i < 32; i += 8)
    out[(size_t)(bx + ty + i) * R + by + tx] = f2bf(tile[tx][ty + i]);
}

// ---------------- GEMM: C[M,N] = A[M,K] * BT[N,K]^T + bias ----------------
// m97-structure: 128xBN tile, BK=32, 4 waves (2x2), global_load_lds(16B) staging.
// + T1 XCD swizzle (nwg % 8 == 0 for all our launches).
template<int BN, bool OUTF32>
__global__ __launch_bounds__(256)
void gemm_bt_kernel(const u16* __restrict__ A, const u16* __restrict__ BT,
                    const float* __restrict__ bias, void* __restrict__ C,
                    int K, int ldc, int Nreal) {
  constexpr int BM = 128, BK = 32;
  constexpr int NF = BN / 32;                     // frags per wave along N
  constexpr int APASS = (BM * BK) / (256 * 8);    // 2
  constexpr int BPASS = (BN * BK) / (256 * 8);    // 2 (BN=128) or 1 (BN=64)
  __shared__ __align__(16) u16 Al[BM * BK];
  __shared__ __align__(16) u16 Bl[BN * BK];
  const int t = threadIdx.x;
  const int w = t >> 6, l = t & 63, lr = l & 15, lg = l >> 4;
  const int wm = w >> 1, wn = w & 1;

  // XCD-aware swizzle of the linear block id (T1; nwg%8==0 guaranteed here)
  const int nwg = gridDim.x * gridDim.y;
  const int id = blockIdx.y * gridDim.x + blockIdx.x;
  const int qq = nwg >> 3;
  const int swz = (id & 7) * qq + (id >> 3);
  const int bx = swz % gridDim.x, by = swz / gridDim.x;

  const int m0 = by * BM, n0 = bx * BN;

  fx4 acc[4][NF] = {};

  for (int k0 = 0; k0 < K; k0 += BK) {
    #pragma unroll
    for (int p = 0; p < APASS; ++p) {
      int c = t + p * 256;  // 16B chunk id; row = c>>2, col8 = (c&3)*8
      async16(A + (size_t)(m0 + (c >> 2)) * K + k0 + (c & 3) * 8, Al + c * 8);
    }
    #pragma unroll
    for (int p = 0; p < BPASS; ++p) {
      int c = t + p * 256;
      async16(BT + (size_t)(n0 + (c >> 2)) * K + k0 + (c & 3) * 8, Bl + c * 8);
    }
    __syncthreads();  // compiler drains vmcnt before barrier
    bhalf8 af[4], bfr[NF];
    #pragma unroll
    for (int m = 0; m < 4; ++m)
      af[m] = *(const bhalf8*)(Al + (wm * 64 + m * 16 + lr) * BK + lg * 8);
    #pragma unroll
    for (int n = 0; n < NF; ++n)
      bfr[n] = *(const bhalf8*)(Bl + (wn * (BN / 2) + n * 16 + lr) * BK + lg * 8);
    #pragma unroll
    for (int m = 0; m < 4; ++m)
      #pragma unroll
      for (int n = 0; n < NF; ++n)
        acc[m][n] = mfma16(af[m], bfr[n], acc[m][n]);
    __syncthreads();
  }

  // epilogue: C/D layout col=lane&15, row=(lane>>4)*4+reg (m89-verified)
  #pragma unroll
  for (int m = 0; m < 4; ++m)
  #pragma unroll
  for (int n = 0; n < NF; ++n)
  #pragma unroll
  for (int r = 0; r < 4; ++r) {
    int gr = m0 + wm * 64 + m * 16 + lg * 4 + r;
    int gc = n0 + wn * (BN / 2) + n * 16 + lr;
    float bv = (gc < Nreal) ? bias[gc] : 0.0f;
    float v = acc[m][n][r] + bv;
    if constexpr (OUTF32) {
      if (gc < Nreal) ((float*)C)[(size_t)gr * ldc + gc] = v;
    } else {
      ((u16*)C)[(size_t)gr * ldc + gc] = f2bf(v);
    }
  }
}

// ---------------- flash attention, causal, D=64, SPLIT-KV ----------------
// Round 10 model: duration = makespan of deepest q-block (32 serial kv-iters)
// with CUs idling in the tail (occ 11.8%). Fix: split kv at 1024 rows.
// qblk 0-7: single chunk, direct output. qblk 8-15: 2 chunks on independent
// blocks -> un-normalized partials (O f32 + {l, mk} per row), merged by
// merge_kernel. Slot table dispatches longest chunks first.
// Per-block machinery unchanged from r10 (verified): 4 waves x 32 q-rows,
// KBLK=64 double-buffered, async16 K (pre-swizzled source), reg-staged V with
// swizzled transpose scatter, ONE barrier per kv-iter, defer-max softmax.
// Swizzle: 16B slot s of row r holds data slot (s ^ (r&7)).
#define KSWZ(row, slot) (((row) << 6) + ((((slot)) ^ ((row) & 7)) << 3))

__device__ const unsigned char SLOT_Q[24] =
    {8,9,10,11,12,13,14,15,15,7,14,6,13,5,12,4,11,3,10,2,9,1,8,0};
__device__ const unsigned char SLOT_C[24] =
    {0,0,0,0,0,0,0,0, 1,0, 1,0, 1,0, 1,0, 1,0, 1,0, 1,0, 1,0};

__global__ __launch_bounds__(256, 3)
void attn_kernel(const u16* __restrict__ qkv, u16* __restrict__ out,
                 float* __restrict__ Opart, float2* __restrict__ MLpart) {
  const int slot = blockIdx.x;
  const int qblk = SLOT_Q[slot], chunk = SLOT_C[slot];
  const int bh = blockIdx.y;
  const int b = bh / NHEAD, h = bh % NHEAD;
  const int t = threadIdx.x, w = t >> 6, l = t & 63;
  const int lr = l & 15, lg = l >> 4;

  __shared__ __align__(16) u16 Kl[2][64 * 64];   // K tile [kv][d], swizzled
  __shared__ __align__(16) u16 Vt[2][64 * 64];   // V^T tile [d][kv], swizzled
  __shared__ __align__(16) u16 Pl[4][32][72];    // per-wave P [qrow][kv], pad 72

  const int q0 = qblk * 128;
  const int qw = q0 + w * 32;                    // this wave's first q-row (32 rows)
  const int kv_begin = chunk << 10;
  const int kv_end = min((qblk + 1) << 7, kv_begin + 1024);

  // Q A-frags for both 16-row sub-tiles (g=0: rows qw..+15, g=1: +16..+31)
  bhalf8 qf[2][2];
  #pragma unroll
  for (int g = 0; g < 2; ++g) {
    const size_t qoff = ((size_t)(b * T_SEQ + qw + g * 16 + lr)) * QKV_LD + h * 64;
    qf[g][0] = *(const bhalf8*)(qkv + qoff + lg * 8);
    qf[g][1] = *(const bhalf8*)(qkv + qoff + 32 + lg * 8);
  }

  constexpr float KSC = 0.125f * 1.44269504089f;  // scale * log2(e)

  fx4 oacc[2][4] = {};
  float m_run[2][4], mk[2][4], thr[2][4], l_acc[2][4];
  #pragma unroll
  for (int g = 0; g < 2; ++g)
    #pragma unroll
    for (int r = 0; r < 4; ++r) {
      m_run[g][r] = -3.0e38f; mk[g][r] = -3.0e38f; thr[g][r] = -3.0e38f; l_acc[g][r] = 0.0f;
    }

  // --- staging thread mappings (256 threads, 2 chunks each) ---
  // chunk c in 0..511: row = c>>3 (kv 0..63), slot = c&7.
  const size_t kvrow_base = (size_t)(b * T_SEQ) * QKV_LD + 1600 + h * 64;

  int4 vpre[2];
  // prologue: issue K(kv_begin) via async16 (pre-swizzled source), V to regs
  #pragma unroll
  for (int p = 0; p < 2; ++p) {
    const int c = t + p * 256;
    const int kr = c >> 3;
    const int ks = (c & 7) ^ (kr & 7);
    const size_t rb = kvrow_base + (size_t)(kv_begin + kr) * QKV_LD;
    async16(qkv + rb + ks * 8, Kl[0] + c * 8);
    vpre[p] = *(const int4*)(qkv + rb + 1600 + (c & 7) * 8);
  }

  for (int kv0 = kv_begin; kv0 < kv_end; kv0 += 64) {
    const int bsel = ((kv0 - kv_begin) >> 6) & 1;
    u16* Klb = Kl[bsel];
    u16* Vtb = Vt[bsel];

    asm volatile("s_waitcnt vmcnt(0)" ::: "memory");  // K in LDS, V in regs
    // scatter V -> Vt[bsel] (transposed, swizzled)
    #pragma unroll
    for (int p = 0; p < 2; ++p) {
      const int c = t + p * 256;
      const int vr = c >> 3;
      const int vc = (c & 7) * 8;
      union { int4 v; u16 u[8]; } vv; vv.v = vpre[p];
      #pragma unroll
      for (int i = 0; i < 8; ++i) {
        int row = vc + i;  // d
        Vtb[(row << 6) + (((vr >> 3) ^ (row & 7)) << 3) + (vr & 7)] = vv.u[i];
      }
    }
    __syncthreads();  // staging visible; nothing in flight, drain is free

    // issue next tile's loads -- they stay in flight across the whole compute
    if (kv0 + 64 < kv_end) {
      #pragma unroll
      for (int p = 0; p < 2; ++p) {
        const int c = t + p * 256;
        const int kr = c >> 3;
        const int ks = (c & 7) ^ (kr & 7);
        const size_t rb = kvrow_base + (size_t)(kv0 + 64 + kr) * QKV_LD;
        async16(qkv + rb + ks * 8, Kl[bsel ^ 1] + c * 8);
        vpre[p] = *(const int4*)(qkv + rb + 1600 + (c & 7) * 8);
      }
    }

    const bool active = (kv0 <= qw + 31);
    if (active) {
      // ---- S_raw = Q K^T (unscaled; scale folded into exp2 fma) ----
      float sv[2][4][4];
      __builtin_amdgcn_s_setprio(1);
      #pragma unroll
      for (int n = 0; n < 4; ++n) {
        bhalf8 k0f = *(const bhalf8*)(Klb + KSWZ(n * 16 + lr, lg));
        bhalf8 k1f = *(const bhalf8*)(Klb + KSWZ(n * 16 + lr, 4 + lg));
        #pragma unroll
        for (int g = 0; g < 2; ++g) {
          fx4 s = {0.f, 0.f, 0.f, 0.f};
          s = mfma16(qf[g][0], k0f, s);
          s = mfma16(qf[g][1], k1f, s);
          #pragma unroll
          for (int r = 0; r < 4; ++r) sv[g][n][r] = s[r];
        }
      }
      __builtin_amdgcn_s_setprio(0);
      if (kv0 + 63 > qw) {  // diagonal overlap: mask kv > q
        #pragma unroll
        for (int g = 0; g < 2; ++g)
          #pragma unroll
          for (int n = 0; n < 4; ++n)
            #pragma unroll
            for (int r = 0; r < 4; ++r)
              if (kv0 + n * 16 + lr > qw + g * 16 + lg * 4 + r) sv[g][n][r] = -1e30f;
      }
      // ---- defer-max check: per-lane max vs raw threshold, wave-uniform ballot ----
      float pm[2][4];
      bool ok = true;
      #pragma unroll
      for (int g = 0; g < 2; ++g)
        #pragma unroll
        for (int r = 0; r < 4; ++r) {
          pm[g][r] = fmaxf(fmaxf(sv[g][0][r], sv[g][1][r]), fmaxf(sv[g][2][r], sv[g][3][r]));
          ok = ok && (pm[g][r] <= thr[g][r]);
        }
      if (!__all(ok)) {
        // slow path (~once per block): full row-max reduce + rescale state
        #pragma unroll
        for (int g = 0; g < 2; ++g)
          #pragma unroll
          for (int r = 0; r < 4; ++r) {
            float mx = pm[g][r] * 0.125f;
            mx = fmaxf(mx, __shfl_xor(mx, 1));
            mx = fmaxf(mx, __shfl_xor(mx, 2));
            mx = fmaxf(mx, __shfl_xor(mx, 4));
            mx = fmaxf(mx, __shfl_xor(mx, 8));
            float mN = fmaxf(m_run[g][r], mx);
            float scl = __expf(m_run[g][r] - mN);   // -inf first time -> 0
            m_run[g][r] = mN;
            mk[g][r] = mN * 1.44269504089f;
            thr[g][r] = 8.0f * mN + 64.0f;          // raw-score form of (m+8)
            l_acc[g][r] *= scl;
            oacc[g][0][r] *= scl; oacc[g][1][r] *= scl;
            oacc[g][2][r] *= scl; oacc[g][3][r] *= scl;
          }
      }
      // ---- common path: P = exp2(S*KSC - mk); per-lane l accumulation ----
      #pragma unroll
      for (int g = 0; g < 2; ++g)
        #pragma unroll
        for (int n = 0; n < 4; ++n)
          #pragma unroll
          for (int r = 0; r < 4; ++r) {
            float p = exp2f(fmaf(sv[g][n][r], KSC, -mk[g][r]));
            l_acc[g][r] += p;
            Pl[w][g * 16 + lg * 4 + r][n * 16 + lr] = f2bf(p);
          }
      asm volatile("s_waitcnt lgkmcnt(0)" ::: "memory");  // cross-lane P visible
      __builtin_amdgcn_sched_barrier(0);                  // guide rule #18
      // ---- O += P V ----
      __builtin_amdgcn_s_setprio(1);
      #pragma unroll
      for (int s = 0; s < 2; ++s) {
        bhalf8 pa0 = *(const bhalf8*)&Pl[w][lr][s * 32 + lg * 8];
        bhalf8 pa1 = *(const bhalf8*)&Pl[w][16 + lr][s * 32 + lg * 8];
        #pragma unroll
        for (int n = 0; n < 4; ++n) {
          bhalf8 vbf = *(const bhalf8*)(Vtb + KSWZ(n * 16 + lr, s * 4 + lg));
          oacc[0][n] = mfma16(pa0, vbf, oacc[0][n]);
          oacc[1][n] = mfma16(pa1, vbf, oacc[1][n]);
        }
      }
      __builtin_amdgcn_s_setprio(0);
    }
  }

  // ---- cross-lane l reduction (common to both epilogues) ----
  #pragma unroll
  for (int g = 0; g < 2; ++g)
    #pragma unroll
    for (int r = 0; r < 4; ++r) {
      float rs = l_acc[g][r];
      rs += __shfl_xor(rs, 1);
      rs += __shfl_xor(rs, 2);
      rs += __shfl_xor(rs, 4);
      rs += __shfl_xor(rs, 8);
      l_acc[g][r] = rs;
    }

  if (qblk < 8) {
    // single chunk: normalize + store bf16 directly
    #pragma unroll
    for (int g = 0; g < 2; ++g) {
      const size_t obase = ((size_t)(b * T_SEQ + qw + g * 16 + lg * 4)) * 1600 + h * 64;
      #pragma unroll
      for (int n = 0; n < 4; ++n)
        #pragma unroll
        for (int r = 0; r < 4; ++r) {
          float v = oacc[g][n][r] / l_acc[g][r];
          out[obase + (size_t)r * 1600 + n * 16 + lr] = f2bf(v);
        }
    }
  } else {
    // partial: un-normalized O (f32) + per-row {l, mk}
    const int pslot = ((qblk - 8) << 1) | chunk;
    const int prow0 = (bh * 16 + pslot) * 128 + w * 32;
    #pragma unroll
    for (int g = 0; g < 2; ++g) {
      #pragma unroll
      for (int n = 0; n < 4; ++n)
        #pragma unroll
        for (int r = 0; r < 4; ++r)
          Opart[(size_t)(prow0 + g * 16 + lg * 4 + r) * 64 + n * 16 + lr] = oacc[g][n][r];
      if (lr == 0) {
        #pragma unroll
        for (int r = 0; r < 4; ++r)
          MLpart[prow0 + g * 16 + lg * 4 + r] = make_float2(l_acc[g][r], mk[g][r]);
      }
    }
  }
}

// ---------------- split-kv merge: 2-way log-sum-exp combine ----------------
// rows 1024..2047 of each (b,h): out = (w0*O0 + w1*O1) / (w0*l0 + w1*l1),
// w_c = exp2(mk_c - max). Each thread handles 4 d-elements of one row.
__global__ __launch_bounds__(256)
void merge_kernel(const float* __restrict__ Opart, const float2* __restrict__ MLpart,
                  u16* __restrict__ out) {
  const int e = blockIdx.x * 256 + threadIdx.x;  // < 50 * 1024 * 16
  const int d4 = (e & 15) << 2;
  const int row1024 = (e >> 4) & 1023;
  const int bh = e >> 14;
  const int b = bh / NHEAD, h = bh % NHEAD;
  const int qblk8 = row1024 >> 7;                // qblk - 8
  const int base0 = (bh * 16 + (qblk8 << 1)) * 128 + (row1024 & 127);
  const int base1 = base0 + 128;

  float2 ml0 = MLpart[base0], ml1 = MLpart[base1];
  float M = fmaxf(ml0.y, ml1.y);
  float w0 = exp2f(ml0.y - M), w1 = exp2f(ml1.y - M);
  float linv = 1.0f / (w0 * ml0.x + w1 * ml1.x);
  float4 o0 = *(const float4*)(Opart + (size_t)base0 * 64 + d4);
  float4 o1 = *(const float4*)(Opart + (size_t)base1 * 64 + d4);
  u16x4 ov;
  ov.x = f2bf((w0 * o0.x + w1 * o1.x) * linv);
  ov.y = f2bf((w0 * o0.y + w1 * o1.y) * linv);
  ov.z = f2bf((w0 * o0.z + w1 * o1.z) * linv);
  ov.w = f2bf((w0 * o0.w + w1 * o1.w) * linv);
  *(u16x4*)(out + ((size_t)(b * T_SEQ + 1024 + row1024)) * 1600 + h * 64 + d4) = ov;
}

extern "C" void kernel_launch(void* const* d_in, const int* in_sizes, int n_in,
                              void* d_out, int out_size, void* d_ws, size_t ws_size,
                              hipStream_t stream) {
  const float* x     = (const float*)d_in[0];  // [2,2048,1600]
  const float* w_qkv = (const float*)d_in[1];  // [1600,4800]
  const float* b_qkv = (const float*)d_in[2];  // [4800]
  const float* w_out = (const float*)d_in[3];  // [1600,1600]
  const float* b_out = (const float*)d_in[4];  // [1600]
  float* out = (float*)d_out;                  // [2,2048,1600] f32

  constexpr size_t NTOK = 4096;  // B*T
  char* ws = (char*)d_ws;
  size_t off = 0;
  u16* xb    = (u16*)(ws + off); off += NTOK * 1600 * 2;              // x bf16
  u16* wqkvT = (u16*)(ws + off); off += (size_t)QKV_LD * 1600 * 2;    // w_qkv^T bf16 (padded rows)
  u16* woutT = (u16*)(ws + off); off += (size_t)WOUT_LD * 1600 * 2;   // w_out^T bf16 (padded rows)
  u16* qkvb  = (u16*)(ws + off); off += NTOK * QKV_LD * 2;            // qkv bf16 (padded ldc)
  u16* attnb = (u16*)(ws + off); off += NTOK * 1600 * 2;              // attn out bf16
  float*  Opart  = (float*)(ws + off);  off += (size_t)50 * 16 * 128 * 64 * 4;  // 26.2 MB
  float2* MLpart = (float2*)(ws + off); off += (size_t)50 * 16 * 128 * 8;       // 0.8 MB
  (void)ws_size; (void)in_sizes; (void)n_in; (void)out_size;

  cvt_bf16_kernel<<<dim3((unsigned)(NTOK * 1600 / 4 / 256)), dim3(256), 0, stream>>>(
      x, xb, (int)(NTOK * 1600 / 4));
  transp_cvt_kernel<<<dim3(4800 / 32, 1600 / 32), dim3(32, 8), 0, stream>>>(
      w_qkv, wqkvT, 1600, 4800);
  transp_cvt_kernel<<<dim3(1600 / 32, 1600 / 32), dim3(32, 8), 0, stream>>>(
      w_out, woutT, 1600, 1600);
  gemm_bt_kernel<128, false><<<dim3(QKV_LD / 128, NTOK / 128), dim3(256), 0, stream>>>(
      xb, wqkvT, b_qkv, qkvb, 1600, QKV_LD, 4800);
  attn_kernel<<<dim3(24, 2 * NHEAD), dim3(256), 0, stream>>>(qkvb, attnb, Opart, MLpart);
  merge_kernel<<<dim3(50 * 1024 * 16 / 256), dim3(256), 0, stream>>>(Opart, MLpart, attnb);
  gemm_bt_kernel<128, true><<<dim3(WOUT_LD / 128, NTOK / 128), dim3(256), 0, stream>>>(
      attnb, woutT, b_out, out, 1600, 1600, 1600);
}